// Round 2
// baseline (334.872 us; speedup 1.0000x reference)
//
#include <hip/hip_runtime.h>

typedef __bf16 bf16x8 __attribute__((ext_vector_type(8)));
typedef __bf16 bf16x4 __attribute__((ext_vector_type(4)));
typedef float f32x4 __attribute__((ext_vector_type(4)));

typedef const __attribute__((address_space(1))) void* gas_t;
typedef __attribute__((address_space(3))) void* las_t;

static constexpr int DIM = 2048;
static constexpr size_t MAT = (size_t)DIM * DIM;  // 4194304 elements

__device__ __forceinline__ float sigmoidf_(float x) { return 1.f / (1.f + __expf(-x)); }

// ---------------------------------------------------------------------------
// fp32 -> bf16 conversion for X, Wq, Wk, Wv, Wo  (grid: (4096, 5), 256 thr)
// ---------------------------------------------------------------------------
__global__ void cvt_kernel(const float* __restrict__ x, const float* __restrict__ wq,
                           const float* __restrict__ wk, const float* __restrict__ wv,
                           const float* __restrict__ wo, __bf16* __restrict__ dst) {
  const float* s;
  switch (blockIdx.y) {
    case 0: s = x; break;
    case 1: s = wq; break;
    case 2: s = wk; break;
    case 3: s = wv; break;
    default: s = wo; break;
  }
  __bf16* d = dst + (size_t)blockIdx.y * MAT;
  size_t i = ((size_t)blockIdx.x * 256 + threadIdx.x) * 4;
  float4 v = *(const float4*)(s + i);
  bf16x4 ov;
  ov[0] = (__bf16)v.x; ov[1] = (__bf16)v.y; ov[2] = (__bf16)v.z; ov[3] = (__bf16)v.w;
  *(bf16x4*)(d + i) = ov;
}

// ---------------------------------------------------------------------------
// 128x128x32 bf16 GEMM body, 2-phase double-buffered: C = A * B^T (+bias, scale)
// A: [M x 2048] bf16 row-major, B: [N x 2048] bf16 row-major.
// Per K-step: ONE barrier; next K-tile's global_load_lds issued before the
// current tile's ds_read+MFMA phase, so the vmcnt(0) drain at the next
// barrier waits on loads that had a full compute phase to land (T3 min-2ph).
// This matters most at 1 block/CU (outproj) where no co-resident block can
// hide the drain.
// ---------------------------------------------------------------------------
template <bool F32OUT>
__device__ __forceinline__ void gemm128(const __bf16* __restrict__ A, const __bf16* __restrict__ B,
                                        const float* __restrict__ bias, bool bias_row, float scale,
                                        void* __restrict__ Cout, int mtile, int ntile,
                                        __bf16* Asm, __bf16* Bsm) {
  const int t = threadIdx.x, lane = t & 63, w = t >> 6;
  const int wrow = (w >> 1) * 64, wcol = (w & 1) * 64;
  const int rbase = mtile * 128, cbase = ntile * 128;
  f32x4 acc[4][4] = {};

  // stage one 128x32 K-tile of A and B into buffer buf
  auto stage = [&](int buf, int k0) {
#pragma unroll
    for (int i = 0; i < 2; ++i) {
      const int o = i * 4096 + w * 1024 + lane * 16;  // byte offset in 128x32 bf16 tile
      const int r = o >> 6;                           // row 0..127
      const int ke = (o & 63) >> 1;                   // element offset in row (0,8,16,24)
      __builtin_amdgcn_global_load_lds((gas_t)(A + (size_t)(rbase + r) * DIM + k0 + ke),
                                       (las_t)(Asm + buf * 4096 + (o >> 1)), 16, 0, 0);
      __builtin_amdgcn_global_load_lds((gas_t)(B + (size_t)(cbase + r) * DIM + k0 + ke),
                                       (las_t)(Bsm + buf * 4096 + (o >> 1)), 16, 0, 0);
    }
  };

  stage(0, 0);
  int p = 0;
  for (int k0 = 0; k0 < DIM; k0 += 32) {
    __syncthreads();  // buf[p] staged (vmcnt drained); buf[p^1] reads from t-1 done
    if (k0 + 32 < DIM) stage(p ^ 1, k0 + 32);  // prefetch; drains at NEXT barrier

    bf16x8 af[4], bf[4];
#pragma unroll
    for (int i = 0; i < 4; ++i)
      af[i] = *(const bf16x8*)(Asm + p * 4096 + (wrow + i * 16 + (lane & 15)) * 32 + (lane >> 4) * 8);
#pragma unroll
    for (int j = 0; j < 4; ++j)
      bf[j] = *(const bf16x8*)(Bsm + p * 4096 + (wcol + j * 16 + (lane & 15)) * 32 + (lane >> 4) * 8);
#pragma unroll
    for (int i = 0; i < 4; ++i)
#pragma unroll
      for (int j = 0; j < 4; ++j)
        acc[i][j] = __builtin_amdgcn_mfma_f32_16x16x32_bf16(af[i], bf[j], acc[i][j], 0, 0, 0);
    p ^= 1;
  }

  // epilogue: C/D layout col = lane&15, row = (lane>>4)*4 + r
#pragma unroll
  for (int i = 0; i < 4; ++i)
#pragma unroll
    for (int j = 0; j < 4; ++j)
#pragma unroll
      for (int r = 0; r < 4; ++r) {
        const int row = rbase + wrow + i * 16 + (lane >> 4) * 4 + r;
        const int col = cbase + wcol + j * 16 + (lane & 15);
        float v = acc[i][j][r] + (bias_row ? bias[row] : bias[col]);
        v *= scale;
        if (F32OUT)
          ((float*)Cout)[(size_t)row * DIM + col] = v;
        else
          ((__bf16*)Cout)[(size_t)row * DIM + col] = (__bf16)v;
      }
}

// ---------------------------------------------------------------------------
// Fused QKV projections. grid (48,16): sel = x>>4 picks Q / K / V^T.
// Q = (X Wq^T + bq) * alpha   (alpha = (1 - 0.1 sig(justice))/sqrt(128))
// K = X Wk^T + bk
// V^T = Wv X^T + bv[row]      (transposed so attention can global_load_lds it)
// ---------------------------------------------------------------------------
__global__ __launch_bounds__(256, 2) void qkv_kernel(
    const __bf16* __restrict__ Xb, const __bf16* __restrict__ Wqb, const __bf16* __restrict__ Wkb,
    const __bf16* __restrict__ Wvb, const float* __restrict__ bq, const float* __restrict__ bk,
    const float* __restrict__ bv, const float* __restrict__ jgate, __bf16* __restrict__ Qo,
    __bf16* __restrict__ Ko, __bf16* __restrict__ Vto) {
  __shared__ __bf16 Asm[2 * 128 * 32];
  __shared__ __bf16 Bsm[2 * 128 * 32];
  const int sel = blockIdx.x >> 4, nt = blockIdx.x & 15, mt = blockIdx.y;
  const __bf16 *A, *B;
  const float* bias;
  __bf16* C;
  bool brow = false;
  float sc = 1.f;
  if (sel == 0) {
    A = Xb; B = Wqb; bias = bq; C = Qo;
    sc = (1.f - 0.1f * sigmoidf_(jgate[0])) * 0.08838834764831843f;  // 1/sqrt(128)
  } else if (sel == 1) {
    A = Xb; B = Wkb; bias = bk; C = Ko;
  } else {
    A = Wvb; B = Xb; bias = bv; C = Vto; brow = true;
  }
  gemm128<false>(A, B, bias, brow, sc, C, mt, nt, Asm, Bsm);
}

// ---------------------------------------------------------------------------
// Output projection: out = Ab Wo^T + bo  (fp32 out)
// ---------------------------------------------------------------------------
__global__ __launch_bounds__(256, 2) void outproj_kernel(const __bf16* __restrict__ Ab,
                                                         const __bf16* __restrict__ Wob,
                                                         const float* __restrict__ bo,
                                                         float* __restrict__ Cout) {
  __shared__ __bf16 Asm[2 * 128 * 32];
  __shared__ __bf16 Bsm[2 * 128 * 32];
  gemm128<true>(Ab, Wob, bo, false, 1.f, Cout, blockIdx.y, blockIdx.x, Asm, Bsm);
}

// ---------------------------------------------------------------------------
// Flash attention. grid (32 qtiles, 16 heads), 256 threads = 4 waves.
// QBLK = 64 query rows/block (16 per wave); 512 blocks -> 2 blocks/CU so a
// block at its barrier drain overlaps a co-resident block's compute (m114
// mechanism; 1 block/CU structurally cannot do this). LDS 73 KiB < 80 KiB.
// K/V double-buffered, prefetch-before-compute, 1 barrier/tile; both-sides
// XOR swizzle (o ^= ((o>>7)&3)<<4) keeps ds_read_b128 at 2-way (free).
// ---------------------------------------------------------------------------
__global__ __launch_bounds__(256) void attn_kernel(const __bf16* __restrict__ Q,
                                                   const __bf16* __restrict__ Kg,
                                                   const __bf16* __restrict__ VT,
                                                   const float* __restrict__ ogate,
                                                   __bf16* __restrict__ O) {
  __shared__ __bf16 Ks[2][4 * 64 * 32];   // 2 x 16 KiB, layout [c][key][32] (swizzled slots)
  __shared__ __bf16 Vs[2][2 * 128 * 32];  // 2 x 16 KiB, layout [cc][d][32] (swizzled slots)
  __shared__ __bf16 Ps[4 * 16 * 72];      // 9 KiB, padded stride 72 (2-way max)
  const int t = threadIdx.x, lane = t & 63, w = t >> 6;  // w in 0..3
  const int h = blockIdx.y, qt = blockIdx.x;             // qt in 0..31
  const float beta = sigmoidf_(ogate[0]) * 0.05f / 2048.0f;

  // per-lane swizzled 8-elem slot offset for K/V reads:
  // slot' = (lane>>4) ^ (row bits 1..2), row = *16 + (lane&15)
  const int rs8 = (((lane >> 4) ^ ((lane >> 1) & 3)) & 3) * 8;

  const int qrow = qt * 64 + w * 16 + (lane & 15);
  bf16x8 qf[4];
#pragma unroll
  for (int c = 0; c < 4; ++c)
    qf[c] = *(const bf16x8*)(Q + (size_t)qrow * DIM + h * 128 + c * 32 + (lane >> 4) * 8);

  f32x4 oacc[8] = {};
  float m_r[4], l_r[4];
#pragma unroll
  for (int r = 0; r < 4; ++r) { m_r[r] = -1e30f; l_r[r] = 0.f; }

  // stage tile kt into buffer buf (LDS dest linear, global source pre-swizzled)
  auto stage = [&](int buf, int kt) {
#pragma unroll
    for (int i = 0; i < 4; ++i) {
      const int o = i * 4096 + w * 1024 + lane * 16;   // linear LDS byte offset, 0..16368
      const int oz = o ^ (((o >> 7) & 3) << 4);        // swizzled logical address
      const int ke = (oz & 63) >> 1;                   // element offset in 32-wide row
      // K tile: [c][key][32]
      const int c = oz >> 12, key = (oz & 4095) >> 6;
      __builtin_amdgcn_global_load_lds(
          (gas_t)(Kg + (size_t)(kt + key) * DIM + h * 128 + c * 32 + ke),
          (las_t)(&Ks[buf][0] + (o >> 1)), 16, 0, 0);
      // V^T tile: [cc][d][32]
      const int cc = oz >> 13, d = (oz & 8191) >> 6;
      __builtin_amdgcn_global_load_lds(
          (gas_t)(VT + (size_t)(h * 128 + d) * DIM + kt + cc * 32 + ke),
          (las_t)(&Vs[buf][0] + (o >> 1)), 16, 0, 0);
    }
  };

  stage(0, 0);
  int p = 0;
  for (int kt = 0; kt < 2048; kt += 64) {
    __syncthreads();  // buf[p] staged (vmcnt drained here); buf[p^1] reads from t-1 done
    if (kt + 64 < 2048) stage(p ^ 1, kt + 64);  // prefetch next tile; drains at NEXT barrier

    // QK^T: s[j] = 16q x 16key block j
    f32x4 s[4];
#pragma unroll
    for (int j = 0; j < 4; ++j) {
      f32x4 a = {};
#pragma unroll
      for (int c = 0; c < 4; ++c) {
        bf16x8 kf = *(const bf16x8*)(&Ks[p][0] + c * 2048 + (j * 16 + (lane & 15)) * 32 + rs8);
        a = __builtin_amdgcn_mfma_f32_16x16x32_bf16(qf[c], kf, a, 0, 0, 0);
      }
      s[j] = a;
    }
    // per-key position bias (the only gate term that survives softmax besides alpha)
#pragma unroll
    for (int j = 0; j < 4; ++j) {
      const float pb = beta * (float)(kt + j * 16 + (lane & 15));
#pragma unroll
      for (int r = 0; r < 4; ++r) s[j][r] += pb;
    }
    // row max over 64 keys: regs then 16-lane butterfly
    float rmax[4];
#pragma unroll
    for (int r = 0; r < 4; ++r)
      rmax[r] = fmaxf(fmaxf(s[0][r], s[1][r]), fmaxf(s[2][r], s[3][r]));
#pragma unroll
    for (int msk = 1; msk < 16; msk <<= 1)
#pragma unroll
      for (int r = 0; r < 4; ++r) rmax[r] = fmaxf(rmax[r], __shfl_xor(rmax[r], msk, 64));

    float al[4];
#pragma unroll
    for (int r = 0; r < 4; ++r) {
      const float mn = fmaxf(m_r[r], rmax[r]);
      al[r] = __expf(m_r[r] - mn);
      m_r[r] = mn;
    }
#pragma unroll
    for (int j = 0; j < 4; ++j)
#pragma unroll
      for (int r = 0; r < 4; ++r) s[j][r] = __expf(s[j][r] - m_r[r]);

    float rs[4];
#pragma unroll
    for (int r = 0; r < 4; ++r) rs[r] = (s[0][r] + s[1][r]) + (s[2][r] + s[3][r]);
#pragma unroll
    for (int msk = 1; msk < 16; msk <<= 1)
#pragma unroll
      for (int r = 0; r < 4; ++r) rs[r] += __shfl_xor(rs[r], msk, 64);
#pragma unroll
    for (int r = 0; r < 4; ++r) l_r[r] = l_r[r] * al[r] + rs[r];
#pragma unroll
    for (int d = 0; d < 8; ++d)
#pragma unroll
      for (int r = 0; r < 4; ++r) oacc[d][r] *= al[r];

    // write P (C-layout -> row-major [16 q][64 key], stride 72).
    // Wave-private region: no barrier needed before the PV reads below
    // (same-wave LDS ordering is enforced by lgkmcnt).
    {
      __bf16* pw = Ps + w * 1152;
#pragma unroll
      for (int j = 0; j < 4; ++j)
#pragma unroll
        for (int r = 0; r < 4; ++r)
          pw[((lane >> 4) * 4 + r) * 72 + j * 16 + (lane & 15)] = (__bf16)s[j][r];
    }

    // PV: oacc[d] += P(16x64) * V(64 x 16d-block)
#pragma unroll
    for (int cc = 0; cc < 2; ++cc) {
      bf16x8 pa = *(const bf16x8*)(Ps + w * 1152 + (lane & 15) * 72 + cc * 32 + (lane >> 4) * 8);
#pragma unroll
      for (int d = 0; d < 8; ++d) {
        bf16x8 vf = *(const bf16x8*)(&Vs[p][0] + cc * 4096 + (d * 16 + (lane & 15)) * 32 + rs8);
        oacc[d] = __builtin_amdgcn_mfma_f32_16x16x32_bf16(pa, vf, oacc[d], 0, 0, 0);
      }
    }
    p ^= 1;
  }

  // epilogue: normalize and store bf16 attention output [S][2048]
#pragma unroll
  for (int d = 0; d < 8; ++d)
#pragma unroll
    for (int r = 0; r < 4; ++r) {
      const int row = qt * 64 + w * 16 + (lane >> 4) * 4 + r;
      const int col = h * 128 + d * 16 + (lane & 15);
      O[(size_t)row * DIM + col] = (__bf16)(oacc[d][r] / l_r[r]);
    }
}

// ---------------------------------------------------------------------------
extern "C" void kernel_launch(void* const* d_in, const int* in_sizes, int n_in,
                              void* d_out, int out_size, void* d_ws, size_t ws_size,
                              hipStream_t stream) {
  const float* X  = (const float*)d_in[0];
  const float* Wq = (const float*)d_in[1];
  const float* bq = (const float*)d_in[2];
  const float* Wk = (const float*)d_in[3];
  const float* bk = (const float*)d_in[4];
  const float* Wv = (const float*)d_in[5];
  const float* bv = (const float*)d_in[6];
  const float* Wo = (const float*)d_in[7];
  const float* bo = (const float*)d_in[8];
  // gates: truth(9), balance(10), order(11), justice(12), harmony(13)
  const float* order_g   = (const float*)d_in[11];
  const float* justice_g = (const float*)d_in[12];

  __bf16* wsb = (__bf16*)d_ws;
  __bf16* Xb  = wsb + 0 * MAT;
  __bf16* Wqb = wsb + 1 * MAT;
  __bf16* Wkb = wsb + 2 * MAT;
  __bf16* Wvb = wsb + 3 * MAT;
  __bf16* Wob = wsb + 4 * MAT;
  __bf16* Qb  = wsb + 5 * MAT;
  __bf16* Kb  = wsb + 6 * MAT;
  __bf16* VTb = wsb + 7 * MAT;
  __bf16* Ab  = Xb;  // alias: X is dead after qkv_kernel (keeps ws use at 64 MB)

  cvt_kernel<<<dim3(4096, 5), 256, 0, stream>>>(X, Wq, Wk, Wv, Wo, wsb);
  qkv_kernel<<<dim3(48, 16), 256, 0, stream>>>(Xb, Wqb, Wkb, Wvb, bq, bk, bv, justice_g,
                                               Qb, Kb, VTb);
  attn_kernel<<<dim3(32, 16), 256, 0, stream>>>(Qb, Kb, VTb, order_g, Ab);
  outproj_kernel<<<dim3(16, 16), 256, 0, stream>>>(Ab, Wob, bo, (float*)d_out);
}

// Round 4
// 318.105 us; speedup vs baseline: 1.0527x; 1.0527x over previous
//
#include <hip/hip_runtime.h>

typedef __bf16 bf16x8 __attribute__((ext_vector_type(8)));
typedef __bf16 bf16x4 __attribute__((ext_vector_type(4)));
typedef float f32x4 __attribute__((ext_vector_type(4)));

typedef const __attribute__((address_space(1))) void* gas_t;
typedef __attribute__((address_space(3))) void* las_t;

static constexpr int DIM = 2048;
static constexpr size_t MAT = (size_t)DIM * DIM;  // 4194304 elements

__device__ __forceinline__ float sigmoidf_(float x) { return 1.f / (1.f + __expf(-x)); }

// ---------------------------------------------------------------------------
// fp32 -> bf16 conversion for X, Wq, Wk, Wv, Wo  (grid: (4096, 5), 256 thr)
// ---------------------------------------------------------------------------
__global__ void cvt_kernel(const float* __restrict__ x, const float* __restrict__ wq,
                           const float* __restrict__ wk, const float* __restrict__ wv,
                           const float* __restrict__ wo, __bf16* __restrict__ dst) {
  const float* s;
  switch (blockIdx.y) {
    case 0: s = x; break;
    case 1: s = wq; break;
    case 2: s = wk; break;
    case 3: s = wv; break;
    default: s = wo; break;
  }
  __bf16* d = dst + (size_t)blockIdx.y * MAT;
  size_t i = ((size_t)blockIdx.x * 256 + threadIdx.x) * 4;
  float4 v = *(const float4*)(s + i);
  bf16x4 ov;
  ov[0] = (__bf16)v.x; ov[1] = (__bf16)v.y; ov[2] = (__bf16)v.z; ov[3] = (__bf16)v.w;
  *(bf16x4*)(d + i) = ov;
}

// ---------------------------------------------------------------------------
// m97-style 128x128x32 bf16 GEMM body: C = A * B^T  (+bias, scale)
// (R1 form: single-buffer, 2 barriers/K-step. The R2 double-buffer variant
//  measured neutral-to-negative -- m99/m100 null reproduced -- reverted.)
// ---------------------------------------------------------------------------
template <bool F32OUT>
__device__ __forceinline__ void gemm128(const __bf16* __restrict__ A, const __bf16* __restrict__ B,
                                        const float* __restrict__ bias, bool bias_row, float scale,
                                        void* __restrict__ Cout, int mtile, int ntile,
                                        __bf16* Asm, __bf16* Bsm) {
  const int t = threadIdx.x, lane = t & 63, w = t >> 6;
  const int wrow = (w >> 1) * 64, wcol = (w & 1) * 64;
  const int rbase = mtile * 128, cbase = ntile * 128;
  f32x4 acc[4][4] = {};

  for (int k0 = 0; k0 < DIM; k0 += 32) {
    __syncthreads();  // previous iteration's LDS reads complete
#pragma unroll
    for (int i = 0; i < 2; ++i) {
      const int o = i * 4096 + w * 1024 + lane * 16;  // byte offset in 128x32 bf16 tile
      const int r = o >> 6;                           // row 0..127
      const int ke = (o & 63) >> 1;                   // element offset in row (0,8,16,24)
      __builtin_amdgcn_global_load_lds((gas_t)(A + (size_t)(rbase + r) * DIM + k0 + ke),
                                       (las_t)(Asm + (o >> 1)), 16, 0, 0);
      __builtin_amdgcn_global_load_lds((gas_t)(B + (size_t)(cbase + r) * DIM + k0 + ke),
                                       (las_t)(Bsm + (o >> 1)), 16, 0, 0);
    }
    __syncthreads();  // compiler drains vmcnt before barrier

    bf16x8 af[4], bf[4];
#pragma unroll
    for (int i = 0; i < 4; ++i)
      af[i] = *(const bf16x8*)(Asm + (wrow + i * 16 + (lane & 15)) * 32 + (lane >> 4) * 8);
#pragma unroll
    for (int j = 0; j < 4; ++j)
      bf[j] = *(const bf16x8*)(Bsm + (wcol + j * 16 + (lane & 15)) * 32 + (lane >> 4) * 8);
#pragma unroll
    for (int i = 0; i < 4; ++i)
#pragma unroll
      for (int j = 0; j < 4; ++j)
        acc[i][j] = __builtin_amdgcn_mfma_f32_16x16x32_bf16(af[i], bf[j], acc[i][j], 0, 0, 0);
  }

  // epilogue: C/D layout col = lane&15, row = (lane>>4)*4 + r
#pragma unroll
  for (int i = 0; i < 4; ++i)
#pragma unroll
    for (int j = 0; j < 4; ++j)
#pragma unroll
      for (int r = 0; r < 4; ++r) {
        const int row = rbase + wrow + i * 16 + (lane >> 4) * 4 + r;
        const int col = cbase + wcol + j * 16 + (lane & 15);
        float v = acc[i][j][r] + (bias_row ? bias[row] : bias[col]);
        v *= scale;
        if (F32OUT)
          ((float*)Cout)[(size_t)row * DIM + col] = v;
        else
          ((__bf16*)Cout)[(size_t)row * DIM + col] = (__bf16)v;
      }
}

// ---------------------------------------------------------------------------
// Fused QKV projections. grid (48,16): sel = x>>4 picks Q / K / V^T.
// ---------------------------------------------------------------------------
__global__ __launch_bounds__(256, 2) void qkv_kernel(
    const __bf16* __restrict__ Xb, const __bf16* __restrict__ Wqb, const __bf16* __restrict__ Wkb,
    const __bf16* __restrict__ Wvb, const float* __restrict__ bq, const float* __restrict__ bk,
    const float* __restrict__ bv, const float* __restrict__ jgate, __bf16* __restrict__ Qo,
    __bf16* __restrict__ Ko, __bf16* __restrict__ Vto) {
  __shared__ __bf16 Asm[128 * 32];
  __shared__ __bf16 Bsm[128 * 32];
  const int sel = blockIdx.x >> 4, nt = blockIdx.x & 15, mt = blockIdx.y;
  const __bf16 *A, *B;
  const float* bias;
  __bf16* C;
  bool brow = false;
  float sc = 1.f;
  if (sel == 0) {
    A = Xb; B = Wqb; bias = bq; C = Qo;
    sc = (1.f - 0.1f * sigmoidf_(jgate[0])) * 0.08838834764831843f;  // 1/sqrt(128)
  } else if (sel == 1) {
    A = Xb; B = Wkb; bias = bk; C = Ko;
  } else {
    A = Wvb; B = Xb; bias = bv; C = Vto; brow = true;
  }
  gemm128<false>(A, B, bias, brow, sc, C, mt, nt, Asm, Bsm);
}

// ---------------------------------------------------------------------------
// Output projection: out = Ab Wo^T + bo  (fp32 out)
// ---------------------------------------------------------------------------
__global__ __launch_bounds__(256, 2) void outproj_kernel(const __bf16* __restrict__ Ab,
                                                         const __bf16* __restrict__ Wob,
                                                         const float* __restrict__ bo,
                                                         float* __restrict__ Cout) {
  __shared__ __bf16 Asm[128 * 32];
  __shared__ __bf16 Bsm[128 * 32];
  gemm128<true>(Ab, Wob, bo, false, 1.f, Cout, blockIdx.y, blockIdx.x, Asm, Bsm);
}

// ---------------------------------------------------------------------------
// Flash attention, SPLIT-K x2. grid (16 qtiles, 16 heads, 2 splits), 512 thr.
// Each block scans HALF the key range (16 tiles) for a 128-row q-tile and
// writes UNNORMALIZED f32 partial O plus per-row (m, l) to workspace; a
// merge kernel combines the two splits. Rationale: attn's total wave count
// was pinned at 8/CU (2048 waves); split-K doubles it to 16/CU so barrier
// drains overlap the co-resident block (m114), while staging bytes per
// output row are UNCHANGED vs R1 (each tile staged once across the splits
// -- avoids the R2 regression).
// LDS cut 82->80 KiB (exactly 2 blocks/CU): Ps padding (stride 72) replaced
// by stride-64 + 3-bit XOR swizzle (elem ^= (q&7)<<3); read pattern stays
// 2-way (free, m136), write unchanged.
// (Resubmission of R3: container-level infra failure, no kernel defect found
//  in OOB / barrier-uniformity / swizzle audits.)
// ---------------------------------------------------------------------------
__global__ __launch_bounds__(512) void attn_kernel(const __bf16* __restrict__ Q,
                                                   const __bf16* __restrict__ Kg,
                                                   const __bf16* __restrict__ VT,
                                                   const float* __restrict__ ogate,
                                                   float* __restrict__ Od,   // split-0 partial O
                                                   float* __restrict__ Ow,   // split-1 partial O
                                                   float* __restrict__ ml) { // [2][16][2048] m, then l
  __shared__ __bf16 Ks[2][4 * 64 * 32];   // 2 x 16 KiB, layout [c][key][32] (swizzled slots)
  __shared__ __bf16 Vs[2][2 * 128 * 32];  // 2 x 16 KiB, layout [cc][d][32] (swizzled slots)
  __shared__ __bf16 Ps[8 * 16 * 64];      // 16 KiB, stride 64 + XOR swizzle
  const int t = threadIdx.x, lane = t & 63, w = t >> 6;
  const int h = blockIdx.y, qt = blockIdx.x, s = blockIdx.z;
  const int kt0 = s * 1024, kt1 = kt0 + 1024;
  const float beta = sigmoidf_(ogate[0]) * 0.05f / 2048.0f;

  // per-lane swizzled 8-elem slot offset for K/V reads:
  // slot' = (lane>>4) ^ (row bits 1..2), row = *16 + (lane&15)
  const int rs8 = (((lane >> 4) ^ ((lane >> 1) & 3)) & 3) * 8;

  const int qrow = qt * 128 + w * 16 + (lane & 15);
  bf16x8 qf[4];
#pragma unroll
  for (int c = 0; c < 4; ++c)
    qf[c] = *(const bf16x8*)(Q + (size_t)qrow * DIM + h * 128 + c * 32 + (lane >> 4) * 8);

  f32x4 oacc[8] = {};
  float m_r[4], l_r[4];
#pragma unroll
  for (int r = 0; r < 4; ++r) { m_r[r] = -1e30f; l_r[r] = 0.f; }

  // stage tile kt into buffer buf (LDS dest linear, global source pre-swizzled)
  auto stage = [&](int buf, int kt) {
#pragma unroll
    for (int i = 0; i < 2; ++i) {
      const int o = i * 8192 + w * 1024 + lane * 16;   // linear LDS byte offset
      const int oz = o ^ (((o >> 7) & 3) << 4);        // swizzled logical address
      const int ke = (oz & 63) >> 1;                   // element offset in 32-wide row
      // K tile: [c][key][32]  (c,key identical from o or oz: XOR touches bits 4-5 only)
      const int c = oz >> 12, key = (oz & 4095) >> 6;
      __builtin_amdgcn_global_load_lds(
          (gas_t)(Kg + (size_t)(kt + key) * DIM + h * 128 + c * 32 + ke),
          (las_t)(&Ks[buf][0] + (o >> 1)), 16, 0, 0);
      // V^T tile: [cc][d][32]
      const int d = (o & 8191) >> 6;
      __builtin_amdgcn_global_load_lds(
          (gas_t)(VT + (size_t)(h * 128 + d) * DIM + kt + i * 32 + ke),
          (las_t)(&Vs[buf][0] + (o >> 1)), 16, 0, 0);
    }
  };

  stage(0, kt0);
  int p = 0;
  for (int kt = kt0; kt < kt1; kt += 64) {
    __syncthreads();  // buf[p] staged (vmcnt drained here); buf[p^1] reads from t-1 done
    if (kt + 64 < kt1) stage(p ^ 1, kt + 64);  // prefetch next tile; drains at NEXT barrier

    // QK^T: sc[j] = 16q x 16key block j
    f32x4 sc[4];
#pragma unroll
    for (int j = 0; j < 4; ++j) {
      f32x4 a = {};
#pragma unroll
      for (int c = 0; c < 4; ++c) {
        bf16x8 kf = *(const bf16x8*)(&Ks[p][0] + c * 2048 + (j * 16 + (lane & 15)) * 32 + rs8);
        a = __builtin_amdgcn_mfma_f32_16x16x32_bf16(qf[c], kf, a, 0, 0, 0);
      }
      sc[j] = a;
    }
    // per-key position bias
#pragma unroll
    for (int j = 0; j < 4; ++j) {
      const float pb = beta * (float)(kt + j * 16 + (lane & 15));
#pragma unroll
      for (int r = 0; r < 4; ++r) sc[j][r] += pb;
    }
    // row max over 64 keys: regs then 16-lane butterfly
    float rmax[4];
#pragma unroll
    for (int r = 0; r < 4; ++r)
      rmax[r] = fmaxf(fmaxf(sc[0][r], sc[1][r]), fmaxf(sc[2][r], sc[3][r]));
#pragma unroll
    for (int msk = 1; msk < 16; msk <<= 1)
#pragma unroll
      for (int r = 0; r < 4; ++r) rmax[r] = fmaxf(rmax[r], __shfl_xor(rmax[r], msk, 64));

    float al[4];
#pragma unroll
    for (int r = 0; r < 4; ++r) {
      const float mn = fmaxf(m_r[r], rmax[r]);
      al[r] = __expf(m_r[r] - mn);
      m_r[r] = mn;
    }
#pragma unroll
    for (int j = 0; j < 4; ++j)
#pragma unroll
      for (int r = 0; r < 4; ++r) sc[j][r] = __expf(sc[j][r] - m_r[r]);

    float rs[4];
#pragma unroll
    for (int r = 0; r < 4; ++r) rs[r] = (sc[0][r] + sc[1][r]) + (sc[2][r] + sc[3][r]);
#pragma unroll
    for (int msk = 1; msk < 16; msk <<= 1)
#pragma unroll
      for (int r = 0; r < 4; ++r) rs[r] += __shfl_xor(rs[r], msk, 64);
#pragma unroll
    for (int r = 0; r < 4; ++r) l_r[r] = l_r[r] * al[r] + rs[r];
#pragma unroll
    for (int d = 0; d < 8; ++d)
#pragma unroll
      for (int r = 0; r < 4; ++r) oacc[d][r] *= al[r];

    // write P: logical [16 q][64 key] per wave, stride 64, elem ^= (q&7)<<3.
    // Wave-private region: same-wave LDS ordering via lgkmcnt, no barrier.
    {
      __bf16* pw = Ps + w * 1024;
#pragma unroll
      for (int j = 0; j < 4; ++j)
#pragma unroll
        for (int r = 0; r < 4; ++r) {
          const int q = (lane >> 4) * 4 + r;
          pw[(q * 64 + j * 16 + (lane & 15)) ^ ((q & 7) << 3)] = (__bf16)sc[j][r];
        }
    }

    // PV: oacc[d] += P(16x64) * V(64 x 16d-block)
#pragma unroll
    for (int cc = 0; cc < 2; ++cc) {
      const int pe = (w * 1024 + (lane & 15) * 64 + cc * 32 + (lane >> 4) * 8) ^ ((lane & 7) << 3);
      bf16x8 pa = *(const bf16x8*)(Ps + pe);
#pragma unroll
      for (int d = 0; d < 8; ++d) {
        bf16x8 vf = *(const bf16x8*)(&Vs[p][0] + cc * 4096 + (d * 16 + (lane & 15)) * 32 + rs8);
        oacc[d] = __builtin_amdgcn_mfma_f32_16x16x32_bf16(pa, vf, oacc[d], 0, 0, 0);
      }
    }
    p ^= 1;
  }

  // epilogue: UNNORMALIZED f32 partial O + per-row (m, l)
  float* Op = (s == 0) ? Od : Ow;
#pragma unroll
  for (int d = 0; d < 8; ++d)
#pragma unroll
    for (int r = 0; r < 4; ++r) {
      const int row = qt * 128 + w * 16 + (lane >> 4) * 4 + r;
      const int col = h * 128 + d * 16 + (lane & 15);
      Op[(size_t)row * DIM + col] = oacc[d][r];
    }
  if ((lane & 15) == 0) {
#pragma unroll
    for (int r = 0; r < 4; ++r) {
      const int row = qt * 128 + w * 16 + (lane >> 4) * 4 + r;
      ml[s * 32768 + h * 2048 + row] = m_r[r];
      ml[65536 + s * 32768 + h * 2048 + row] = l_r[r];
    }
  }
}

// ---------------------------------------------------------------------------
// Split-K merge: Ab = (e^{m1-M} O1 + e^{m2-M} O2) / (e^{m1-M} l1 + e^{m2-M} l2)
// grid (4096), 256 thr, 4 f32 elems/thread. ~40 MB traffic, HBM-bound ~7 us.
// ---------------------------------------------------------------------------
__global__ void merge_kernel(const float* __restrict__ O1, const float* __restrict__ O2,
                             const float* __restrict__ ml, __bf16* __restrict__ Ab) {
  const size_t i = ((size_t)blockIdx.x * 256 + threadIdx.x) * 4;
  const int row = (int)(i >> 11), col = (int)(i & 2047), h = col >> 7;
  const int mi = h * 2048 + row;
  const float m1 = ml[mi], m2 = ml[32768 + mi];
  const float l1 = ml[65536 + mi], l2 = ml[98304 + mi];
  const float M = fmaxf(m1, m2);
  const float a1 = __expf(m1 - M), a2 = __expf(m2 - M);
  const float inv = 1.f / (a1 * l1 + a2 * l2);
  const float4 o1 = *(const float4*)(O1 + i);
  const float4 o2 = *(const float4*)(O2 + i);
  bf16x4 ov;
  ov[0] = (__bf16)((a1 * o1.x + a2 * o2.x) * inv);
  ov[1] = (__bf16)((a1 * o1.y + a2 * o2.y) * inv);
  ov[2] = (__bf16)((a1 * o1.z + a2 * o2.z) * inv);
  ov[3] = (__bf16)((a1 * o1.w + a2 * o2.w) * inv);
  *(bf16x4*)(Ab + i) = ov;
}

// ---------------------------------------------------------------------------
extern "C" void kernel_launch(void* const* d_in, const int* in_sizes, int n_in,
                              void* d_out, int out_size, void* d_ws, size_t ws_size,
                              hipStream_t stream) {
  const float* X  = (const float*)d_in[0];
  const float* Wq = (const float*)d_in[1];
  const float* bq = (const float*)d_in[2];
  const float* Wk = (const float*)d_in[3];
  const float* bk = (const float*)d_in[4];
  const float* Wv = (const float*)d_in[5];
  const float* bv = (const float*)d_in[6];
  const float* Wo = (const float*)d_in[7];
  const float* bo = (const float*)d_in[8];
  // gates: truth(9), balance(10), order(11), justice(12), harmony(13)
  const float* order_g   = (const float*)d_in[11];
  const float* justice_g = (const float*)d_in[12];

  __bf16* wsb = (__bf16*)d_ws;
  __bf16* Xb  = wsb + 0 * MAT;
  __bf16* Wqb = wsb + 1 * MAT;
  __bf16* Wkb = wsb + 2 * MAT;
  __bf16* Wvb = wsb + 3 * MAT;
  __bf16* Wob = wsb + 4 * MAT;
  __bf16* Qb  = wsb + 5 * MAT;
  __bf16* Kb  = wsb + 6 * MAT;
  __bf16* VTb = wsb + 7 * MAT;
  __bf16* Ab  = Xb;  // alias: X dead after qkv_kernel
  // split-K scratch (all in otherwise-dead space):
  float* Opart0 = (float*)d_out;            // 16 MB f32, overwritten later by outproj
  float* Opart1 = (float*)(wsb + 1 * MAT);  // slots Wqb+Wkb (dead after qkv) = 16 MB f32
  float* mlbuf  = (float*)(wsb + 3 * MAT);  // slot Wvb (dead after qkv), 512 KB used

  cvt_kernel<<<dim3(4096, 5), 256, 0, stream>>>(X, Wq, Wk, Wv, Wo, wsb);
  qkv_kernel<<<dim3(48, 16), 256, 0, stream>>>(Xb, Wqb, Wkb, Wvb, bq, bk, bv, justice_g,
                                               Qb, Kb, VTb);
  attn_kernel<<<dim3(16, 16, 2), 512, 0, stream>>>(Qb, Kb, VTb, order_g, Opart0, Opart1, mlbuf);
  merge_kernel<<<dim3(4096), 256, 0, stream>>>(Opart0, Opart1, mlbuf, Ab);
  outproj_kernel<<<dim3(16, 16), 256, 0, stream>>>(Ab, Wob, bo, (float*)d_out);
}